// Round 3
// baseline (820.485 us; speedup 1.0000x reference)
//
#include <hip/hip_runtime.h>

typedef float f32x4 __attribute__((ext_vector_type(4)));
typedef float f32x16 __attribute__((ext_vector_type(16)));
typedef int i32x4 __attribute__((ext_vector_type(4)));
typedef int i32x8 __attribute__((ext_vector_type(8)));

#define M_DIM 16384L
#define N_DIM 4096L
#define K_DIM 4096L

// ---------------------------------------------------------------------------
// f32 -> OCP e4m3fn, RNE + saturation, bit-exact software version.
// ---------------------------------------------------------------------------
__device__ __forceinline__ unsigned int f32_to_e4m3(float x, float scale) {
  float v = fminf(fmaxf(x * scale, -448.f), 448.f);
  unsigned int u = __float_as_uint(v);
  unsigned int s = (u >> 24) & 0x80u;
  float ax = fabsf(v);
  unsigned int ua = __float_as_uint(ax);
  unsigned int subn = (unsigned int)rintf(ax * 512.0f);   // 0..8, RNE (subnormals)
  unsigned int r = ua + 0x7FFFFu + ((ua >> 20) & 1u);     // RNE to 3 mantissa bits
  unsigned int nrm = ((r >> 20) & 0x7FFu) - 960u;         // rebias 127 -> 7
  unsigned int mag = (ax < 0.015625f) ? subn : nrm;
  return mag | s;
}

__device__ __forceinline__ unsigned int pack4_e4m3(float4 v, float scale) {
  return f32_to_e4m3(v.x, scale) | (f32_to_e4m3(v.y, scale) << 8) |
         (f32_to_e4m3(v.z, scale) << 16) | (f32_to_e4m3(v.w, scale) << 24);
}

// ---------------------------------------------------------------------------
// Kernel 1: f32 -> packed e4m3 quantize (memory-bound).
// ---------------------------------------------------------------------------
__global__ __launch_bounds__(256) void quant_fp8(const float* __restrict__ in,
                                                 unsigned int* __restrict__ out,
                                                 float scale) {
  const long i = (long)blockIdx.x * 256 + threadIdx.x;
  out[i] = pack4_e4m3(reinterpret_cast<const float4*>(in)[i], scale);
}

// ---------------------------------------------------------------------------
// Shared helpers
// ---------------------------------------------------------------------------
__device__ __forceinline__ void gld_lds16(const unsigned char* g, unsigned char* l) {
  __builtin_amdgcn_global_load_lds(
      (const __attribute__((address_space(1))) unsigned int*)g,
      (__attribute__((address_space(3))) unsigned int*)l,
      16, 0, 0);
}

__device__ __forceinline__ uint4 quant16(const float* p, float scale) {
  const float4* q = reinterpret_cast<const float4*>(p);
  uint4 r;
  r.x = pack4_e4m3(q[0], scale);
  r.y = pack4_e4m3(q[1], scale);
  r.z = pack4_e4m3(q[2], scale);
  r.w = pack4_e4m3(q[3], scale);
  return r;
}

// two ds_read_b128 at swizzled 16B units p_lo, p_lo^1 -> 32B K-fragment
__device__ __forceinline__ i32x8 ldfrag(const unsigned char* p, int p_lo) {
  i32x4 lo = *reinterpret_cast<const i32x4*>(p + p_lo * 16);
  i32x4 hi = *reinterpret_cast<const i32x4*>(p + (p_lo ^ 1) * 16);
  return i32x8{lo[0], lo[1], lo[2], lo[3], hi[0], hi[1], hi[2], hi[3]};
}

// fmtA=fmtB=0 (e4m3), scales = e8m0 127 = 1.0 -> bit-exact plain fp8 matmul
#define MFMA_SC(a, b, c) \
  __builtin_amdgcn_mfma_scale_f32_32x32x64_f8f6f4((a), (b), (c), 0, 0, 0, 0x7F7F7F7F, 0, 0x7F7F7F7F)

#define BARRIER() asm volatile("s_barrier" ::: "memory")

// ---------------------------------------------------------------------------
// Kernel 2 (main path): 256x256 tile, BK=64, 8 waves, deep-pipelined
// schedule (T3+T4): triple-buffered LDS, tile kt+2 staged while computing kt,
// one counted vmcnt(4) per K-tile (never 0 in steady state), raw s_barrier
// (no __syncthreads -> no vmcnt(0) drain), setprio around MFMA clusters (T5),
// bijective XCD block swizzle (T1).
//
// LDS: sA/sB = 3 buffers x 256 rows x 64 B (16B-unit XOR swizzle, key
// (row>>1)&3, verified at bank floor in R1/R2). 96 KB total -> 1 block/CU.
//
// Pipeline ledger (per thread, 4 loads/K-tile, in-order vmcnt retirement):
//   prologue: stage tile0 (buf0), tile1 (buf1); vmcnt(4) retires tile0; bar.
//   iter kt: phases 0..3 read buf[kt%3] (tile kt), each phase issues one
//   half-tile load of tile kt+2 into buf[(kt+2)%3] (free since tile kt-1
//   finished last iter).  End of phase 3: vmcnt(4) retires tile kt+1's 4
//   loads (oldest in flight), then s_barrier publishes them -> iter kt+1
//   reads are safe.  Tail: kt>=62 stages nothing, waits vmcnt(0).
// ---------------------------------------------------------------------------
__global__ __launch_bounds__(512, 2) void gemm_fp8_256(
    const unsigned char* __restrict__ A8, const unsigned char* __restrict__ B8,
    const float* __restrict__ bias, float* __restrict__ C) {
  __shared__ unsigned char sA[3 * 16384];
  __shared__ unsigned char sB[3 * 16384];

  const int t = threadIdx.x;
  const int lane = t & 63;
  const int w = t >> 6;   // wave 0..7
  const int wm = w >> 2;  // 2 (M) x 4 (N) wave grid; wave owns 128x64 of C
  const int wn = w & 3;

  // T1: XCD-aware bijective swizzle of the 1024-block grid (1024 % 8 == 0)
  const int bid = (int)blockIdx.y * 16 + (int)blockIdx.x;  // grid = (16, 64)
  const int swz = (bid & 7) * 128 + (bid >> 3);
  const long bx = swz & 15;   // N tile (16)
  const long by = swz >> 4;   // M tile (64)

  f32x16 acc[4][2] = {};

  // staging geometry: per operand half-tile = 128 rows x 64 B = 8 KB =
  // 1 x gld_lds16 per thread. Thread t stages chunk t: row t>>2, LDS unit
  // t&3; global unit is XOR-swizzled by row bits 1-2.
  const int sr = t >> 2;                    // row within half (0..127)
  const int sc = (t & 3) ^ ((t >> 3) & 3);  // swizzled source 16B unit
  // pointers are kept pointing at tile kt+2 inside the loop (init: tile 2)
  const unsigned char* srcA0 = A8 + (by * 256 + sr) * K_DIM + sc * 16 + 128;
  const unsigned char* srcA1 = A8 + (by * 256 + 128 + sr) * K_DIM + sc * 16 + 128;
  const unsigned char* srcB0 = B8 + (bx * 256 + sr) * K_DIM + sc * 16 + 128;
  const unsigned char* srcB1 = B8 + (bx * 256 + 128 + sr) * K_DIM + sc * 16 + 128;
  const int wofs = w * 1024;  // wave-uniform LDS dest base; HW adds lane*16

  // fragment geometry (mfma_scale 32x32x64): lane holds row lane&31,
  // K-units 2*(lane>>5), +1; swizzled positions p_lo, p_lo^1.
  const int r32 = lane & 31;
  const int key = (lane >> 1) & 3;
  const int p_lo = ((lane >> 5) << 1) ^ key;
  const int arow = wm * 128 + r32;  // + mi*32
  const int brow = wn * 64 + r32;   // + nj*32

  // ---- prologue: stage tile 0 -> buf0, tile 1 -> buf1 (order matters) ----
  gld_lds16(srcA0 - 128, sA + wofs);
  gld_lds16(srcA1 - 128, sA + 8192 + wofs);
  gld_lds16(srcB0 - 128, sB + wofs);
  gld_lds16(srcB1 - 128, sB + 8192 + wofs);
  gld_lds16(srcA0 - 64, sA + 16384 + wofs);
  gld_lds16(srcA1 - 64, sA + 16384 + 8192 + wofs);
  gld_lds16(srcB0 - 64, sB + 16384 + wofs);
  gld_lds16(srcB1 - 64, sB + 16384 + 8192 + wofs);
  asm volatile("s_waitcnt vmcnt(4)" ::: "memory");  // tile 0 landed
  BARRIER();                                        // publish

  int b = 0;  // buffer holding tile kt
  for (int kt = 0; kt < 64; ++kt) {
    int b2 = b + 2;
    if (b2 >= 3) b2 -= 3;
    const unsigned char* sAb = sA + b * 16384;
    const unsigned char* sBb = sB + b * 16384;
    unsigned char* dA = sA + b2 * 16384 + wofs;
    unsigned char* dB = sB + b2 * 16384 + wofs;
    const bool st = kt < 62;  // tile kt+2 exists

    // ---- phase 0: B frags + A frag 0; stage A-half0 of tile kt+2
    i32x8 bf0 = ldfrag(sBb + brow * 64, p_lo);
    i32x8 bf1 = ldfrag(sBb + (brow + 32) * 64, p_lo);
    i32x8 af = ldfrag(sAb + arow * 64, p_lo);
    if (st) gld_lds16(srcA0, dA);
    BARRIER();
    __builtin_amdgcn_s_setprio(1);
    acc[0][0] = MFMA_SC(af, bf0, acc[0][0]);
    acc[0][1] = MFMA_SC(af, bf1, acc[0][1]);
    __builtin_amdgcn_s_setprio(0);
    BARRIER();

    // ---- phase 1: A frag 1; stage A-half1
    af = ldfrag(sAb + (arow + 32) * 64, p_lo);
    if (st) gld_lds16(srcA1, dA + 8192);
    BARRIER();
    __builtin_amdgcn_s_setprio(1);
    acc[1][0] = MFMA_SC(af, bf0, acc[1][0]);
    acc[1][1] = MFMA_SC(af, bf1, acc[1][1]);
    __builtin_amdgcn_s_setprio(0);
    BARRIER();

    // ---- phase 2: A frag 2; stage B-half0
    af = ldfrag(sAb + (arow + 64) * 64, p_lo);
    if (st) gld_lds16(srcB0, dB);
    BARRIER();
    __builtin_amdgcn_s_setprio(1);
    acc[2][0] = MFMA_SC(af, bf0, acc[2][0]);
    acc[2][1] = MFMA_SC(af, bf1, acc[2][1]);
    __builtin_amdgcn_s_setprio(0);
    BARRIER();

    // ---- phase 3: A frag 3; stage B-half1; counted vmcnt; publish
    af = ldfrag(sAb + (arow + 96) * 64, p_lo);
    if (st) gld_lds16(srcB1, dB + 8192);
    BARRIER();
    __builtin_amdgcn_s_setprio(1);
    acc[3][0] = MFMA_SC(af, bf0, acc[3][0]);
    acc[3][1] = MFMA_SC(af, bf1, acc[3][1]);
    __builtin_amdgcn_s_setprio(0);
    if (st) {
      asm volatile("s_waitcnt vmcnt(4)" ::: "memory");  // tile kt+1 landed
    } else {
      asm volatile("s_waitcnt vmcnt(0)" ::: "memory");  // tail drain
    }
    BARRIER();  // publish tile kt+1

    srcA0 += 64; srcA1 += 64; srcB0 += 64; srcB1 += 64;
    if (++b == 3) b = 0;
  }

  // ---- epilogue: 32x32 C/D map: col = lane&31, row = (r&3)+8*(r>>2)+4*(lane>>5)
  const int mrow = 4 * (lane >> 5);
  const long gm_base = by * 256 + wm * 128;
  const long gn_base = bx * 256 + wn * 64 + r32;
#pragma unroll
  for (int nj = 0; nj < 2; ++nj) {
    const long gn = gn_base + nj * 32;
    const float bv = bias[gn];
#pragma unroll
    for (int mi = 0; mi < 4; ++mi) {
#pragma unroll
      for (int r = 0; r < 16; ++r) {
        const long gm = gm_base + mi * 32 + (r & 3) + 8 * (r >> 2) + mrow;
        C[gm * N_DIM + gn] = acc[mi][nj][r] * 4.0f + bv;
      }
    }
  }
}

// ---------------------------------------------------------------------------
// Fallback kernel (scratch-constrained paths): R2-verified 128x128 MX kernel
// with fused in-register quantization during staging.
// ---------------------------------------------------------------------------
template <bool FA, bool FB>
__global__ __launch_bounds__(256) void gemm_fp8_fb(const unsigned char* __restrict__ A8,
                                                   const float* __restrict__ Af,
                                                   const unsigned char* __restrict__ B8,
                                                   const float* __restrict__ Bf,
                                                   const float* __restrict__ bias,
                                                   float* __restrict__ C) {
  __shared__ unsigned char sA[128 * 64];
  __shared__ unsigned char sB[128 * 64];

  const int t = threadIdx.x;
  const int lane = t & 63;
  const int w = t >> 6;
  const int wm = w >> 1;
  const int wn = w & 1;
  const long bx = blockIdx.x;
  const long by = blockIdx.y;

  f32x16 acc[2][2] = {};

  const int l0 = w * 64 + lane;
  const int l1 = l0 + 256;
  const int r0 = l0 >> 2, c0 = (l0 & 3) ^ ((l0 >> 3) & 3);
  const int r1 = l1 >> 2, c1 = (l1 & 3) ^ ((l1 >> 3) & 3);

  const unsigned char* gA0 = nullptr; const unsigned char* gA1 = nullptr;
  const float* fA0 = nullptr;         const float* fA1 = nullptr;
  if constexpr (FA) {
    fA0 = Af + (by * 128 + r0) * K_DIM + c0 * 16;
    fA1 = Af + (by * 128 + r1) * K_DIM + c1 * 16;
  } else {
    gA0 = A8 + (by * 128 + r0) * K_DIM + c0 * 16;
    gA1 = A8 + (by * 128 + r1) * K_DIM + c1 * 16;
  }
  const unsigned char* gB0 = nullptr; const unsigned char* gB1 = nullptr;
  const float* fB0 = nullptr;         const float* fB1 = nullptr;
  if constexpr (FB) {
    fB0 = Bf + (bx * 128 + r0) * K_DIM + c0 * 16;
    fB1 = Bf + (bx * 128 + r1) * K_DIM + c1 * 16;
  } else {
    gB0 = B8 + (bx * 128 + r0) * K_DIM + c0 * 16;
    gB1 = B8 + (bx * 128 + r1) * K_DIM + c1 * 16;
  }

  unsigned char* lA0 = sA + w * 1024;
  unsigned char* lA1 = sA + 4096 + w * 1024;
  unsigned char* lB0 = sB + w * 1024;
  unsigned char* lB1 = sB + 4096 + w * 1024;

  const int r32 = lane & 31;
  const int key = (lane >> 1) & 3;
  const int p_lo = ((lane >> 5) << 1) ^ key;
  const unsigned char* sAw = sA + wm * 4096;
  const unsigned char* sBw = sB + wn * 4096;

  for (int kt = 0; kt < (int)(K_DIM / 64); ++kt) {
    if constexpr (FA) {
      *reinterpret_cast<uint4*>(sA + l0 * 16) = quant16(fA0, 0.5f);
      *reinterpret_cast<uint4*>(sA + l1 * 16) = quant16(fA1, 0.5f);
      fA0 += 64; fA1 += 64;
    } else {
      gld_lds16(gA0, lA0);
      gld_lds16(gA1, lA1);
      gA0 += 64; gA1 += 64;
    }
    if constexpr (FB) {
      *reinterpret_cast<uint4*>(sB + l0 * 16) = quant16(fB0, 1.0f);
      *reinterpret_cast<uint4*>(sB + l1 * 16) = quant16(fB1, 1.0f);
      fB0 += 64; fB1 += 64;
    } else {
      gld_lds16(gB0, lB0);
      gld_lds16(gB1, lB1);
      gB0 += 64; gB1 += 64;
    }
    __syncthreads();

    i32x8 af[2], bf[2];
#pragma unroll
    for (int i = 0; i < 2; ++i) {
      af[i] = ldfrag(sAw + (i * 32 + r32) * 64, p_lo);
      bf[i] = ldfrag(sBw + (i * 32 + r32) * 64, p_lo);
    }

#pragma unroll
    for (int i = 0; i < 2; ++i) {
#pragma unroll
      for (int j = 0; j < 2; ++j) {
        acc[i][j] = MFMA_SC(af[i], bf[j], acc[i][j]);
      }
    }
    __syncthreads();
  }

  const int mrow = 4 * (lane >> 5);
  const long gm_base = by * 128 + wm * 64;
  const long gn_base = bx * 128 + wn * 64 + r32;
#pragma unroll
  for (int nj = 0; nj < 2; ++nj) {
    const long gn = gn_base + nj * 32;
    const float bv = bias[gn];
#pragma unroll
    for (int mi = 0; mi < 2; ++mi) {
#pragma unroll
      for (int r = 0; r < 16; ++r) {
        const long gm = gm_base + mi * 32 + (r & 3) + 8 * (r >> 2) + mrow;
        C[gm * N_DIM + gn] = acc[mi][nj][r] * 4.0f + bv;
      }
    }
  }
}

// ---------------------------------------------------------------------------
extern "C" void kernel_launch(void* const* d_in, const int* in_sizes, int n_in,
                              void* d_out, int out_size, void* d_ws, size_t ws_size,
                              hipStream_t stream) {
  const float* inp = (const float*)d_in[0];   // [4,4096,4096] f32
  const float* wgt = (const float*)d_in[1];   // [4096,4096] f32 (fp8 values upcast by harness)
  const float* bias = (const float*)d_in[2];  // [4096] f32
  float* out = (float*)d_out;

  const size_t A_BYTES = (size_t)(M_DIM * K_DIM);  // 64 MB
  const size_t B_BYTES = (size_t)(N_DIM * K_DIM);  // 16 MB

  if (ws_size >= A_BYTES + B_BYTES) {
    // main path: pre-quantize both operands into d_ws, 256^2 pipelined GEMM
    unsigned char* aq = (unsigned char*)d_ws;
    unsigned char* wq = (unsigned char*)d_ws + A_BYTES;
    quant_fp8<<<dim3((unsigned)(M_DIM * K_DIM / 1024)), dim3(256), 0, stream>>>(
        inp, (unsigned int*)aq, 0.5f);
    quant_fp8<<<dim3((unsigned)(N_DIM * K_DIM / 1024)), dim3(256), 0, stream>>>(
        wgt, (unsigned int*)wq, 1.0f);
    gemm_fp8_256<<<dim3(16, 64), dim3(512), 0, stream>>>(aq, wq, bias, out);
  } else if (ws_size >= B_BYTES) {
    unsigned char* wq = (unsigned char*)d_ws;
    quant_fp8<<<dim3((unsigned)(N_DIM * K_DIM / 1024)), dim3(256), 0, stream>>>(
        wgt, (unsigned int*)wq, 1.0f);
    gemm_fp8_fb<true, false><<<dim3((unsigned)(N_DIM / 128), (unsigned)(M_DIM / 128)),
                               dim3(256), 0, stream>>>(nullptr, inp, wq, nullptr, bias, out);
  } else {
    gemm_fp8_fb<true, true><<<dim3((unsigned)(N_DIM / 128), (unsigned)(M_DIM / 128)),
                              dim3(256), 0, stream>>>(nullptr, inp, nullptr, wgt, bias, out);
  }
}

// Round 4
// 790.658 us; speedup vs baseline: 1.0377x; 1.0377x over previous
//
#include <hip/hip_runtime.h>

typedef float f32x4 __attribute__((ext_vector_type(4)));
typedef float f32x16 __attribute__((ext_vector_type(16)));
typedef int i32x4 __attribute__((ext_vector_type(4)));
typedef int i32x8 __attribute__((ext_vector_type(8)));

#define M_DIM 16384L
#define N_DIM 4096L
#define K_DIM 4096L

// ---------------------------------------------------------------------------
// f32 -> OCP e4m3fn, RNE + saturation, bit-exact software version.
// ---------------------------------------------------------------------------
__device__ __forceinline__ unsigned int f32_to_e4m3(float x, float scale) {
  float v = fminf(fmaxf(x * scale, -448.f), 448.f);
  unsigned int u = __float_as_uint(v);
  unsigned int s = (u >> 24) & 0x80u;
  float ax = fabsf(v);
  unsigned int ua = __float_as_uint(ax);
  unsigned int subn = (unsigned int)rintf(ax * 512.0f);   // 0..8, RNE (subnormals)
  unsigned int r = ua + 0x7FFFFu + ((ua >> 20) & 1u);     // RNE to 3 mantissa bits
  unsigned int nrm = ((r >> 20) & 0x7FFu) - 960u;         // rebias 127 -> 7
  unsigned int mag = (ax < 0.015625f) ? subn : nrm;
  return mag | s;
}

__device__ __forceinline__ unsigned int pack4_e4m3(float4 v, float scale) {
  return f32_to_e4m3(v.x, scale) | (f32_to_e4m3(v.y, scale) << 8) |
         (f32_to_e4m3(v.z, scale) << 16) | (f32_to_e4m3(v.w, scale) << 24);
}

// ---------------------------------------------------------------------------
// Kernel 1: f32 -> packed e4m3 quantize (memory-bound).
// ---------------------------------------------------------------------------
__global__ __launch_bounds__(256) void quant_fp8(const float* __restrict__ in,
                                                 unsigned int* __restrict__ out,
                                                 float scale) {
  const long i = (long)blockIdx.x * 256 + threadIdx.x;
  out[i] = pack4_e4m3(reinterpret_cast<const float4*>(in)[i], scale);
}

// ---------------------------------------------------------------------------
// Shared helpers
// ---------------------------------------------------------------------------
__device__ __forceinline__ void gld_lds16(const unsigned char* g, unsigned char* l) {
  __builtin_amdgcn_global_load_lds(
      (const __attribute__((address_space(1))) unsigned int*)g,
      (__attribute__((address_space(3))) unsigned int*)l,
      16, 0, 0);
}

__device__ __forceinline__ uint4 quant16(const float* p, float scale) {
  const float4* q = reinterpret_cast<const float4*>(p);
  uint4 r;
  r.x = pack4_e4m3(q[0], scale);
  r.y = pack4_e4m3(q[1], scale);
  r.z = pack4_e4m3(q[2], scale);
  r.w = pack4_e4m3(q[3], scale);
  return r;
}

// two ds_read_b128 at swizzled 16B units p_lo, p_lo^1 -> 32B K-fragment
__device__ __forceinline__ i32x8 ldfrag(const unsigned char* p, int p_lo) {
  i32x4 lo = *reinterpret_cast<const i32x4*>(p + p_lo * 16);
  i32x4 hi = *reinterpret_cast<const i32x4*>(p + (p_lo ^ 1) * 16);
  return i32x8{lo[0], lo[1], lo[2], lo[3], hi[0], hi[1], hi[2], hi[3]};
}

// fmtA=fmtB=0 (e4m3), scales = e8m0 127 = 1.0 -> bit-exact plain fp8 matmul
#define MFMA_SC(a, b, c) \
  __builtin_amdgcn_mfma_scale_f32_32x32x64_f8f6f4((a), (b), (c), 0, 0, 0, 0x7F7F7F7F, 0, 0x7F7F7F7F)

#define BARRIER() asm volatile("s_barrier" ::: "memory")

// ---------------------------------------------------------------------------
// Kernel 2 (main path): 256x256 tile, BK=64, 8 waves, deep-pipelined
// schedule: triple-buffered LDS, tile kt+2 staged while computing kt,
// one counted vmcnt(4) per K-tile (never 0 in steady state), raw s_barrier
// (no __syncthreads -> no vmcnt(0) drain), setprio around MFMA clusters,
// bijective XCD block swizzle.
//
// R3 post-mortem fix: TWO phases per K-tile (4 MFMA each), 4 barriers/K-tile
// instead of 8 -- R3's 2-MFMA phases (~137 SIMD-cyc matrix work) were too
// fine against fixed per-phase costs (2 barrier round-trips + ds_read
// latency) with 1 block/CU and no cross-block TLP. 4-MFMA phases match the
// verified m201 template's work-per-barrier ratio (~270 SIMD-cyc).
//
// Pipeline ledger (per thread, 4 loads/K-tile, in-order vmcnt retirement):
//   prologue: stage tile0 (buf0), tile1 (buf1); vmcnt(4) retires tile0; bar.
//   iter kt: phase A reads buf[kt%3] B-frags + A-frags 0,1; stages A-halves
//   of tile kt+2 into buf[(kt+2)%3]; barrier; 4 MFMA; barrier.
//   phase B reads A-frags 2,3; stages B-halves of tile kt+2; barrier;
//   4 MFMA; vmcnt(4) retires tile kt+1's 4 loads (oldest of the 8 in
//   flight); barrier publishes tile kt+1.  Tail: kt>=62 stages nothing;
//   final iters drain with vmcnt(0).
// ---------------------------------------------------------------------------
__global__ __launch_bounds__(512, 2) void gemm_fp8_256(
    const unsigned char* __restrict__ A8, const unsigned char* __restrict__ B8,
    const float* __restrict__ bias, float* __restrict__ C) {
  __shared__ unsigned char sA[3 * 16384];
  __shared__ unsigned char sB[3 * 16384];

  const int t = threadIdx.x;
  const int lane = t & 63;
  const int w = t >> 6;   // wave 0..7
  const int wm = w >> 2;  // 2 (M) x 4 (N) wave grid; wave owns 128x64 of C
  const int wn = w & 3;

  // XCD-aware bijective swizzle of the 1024-block grid (1024 % 8 == 0)
  const int bid = (int)blockIdx.y * 16 + (int)blockIdx.x;  // grid = (16, 64)
  const int swz = (bid & 7) * 128 + (bid >> 3);
  const long bx = swz & 15;   // N tile (16)
  const long by = swz >> 4;   // M tile (64)

  f32x16 acc[4][2] = {};

  // staging geometry: per operand half-tile = 128 rows x 64 B = 8 KB =
  // 1 x gld_lds16 per thread. Thread t stages chunk t: row t>>2, LDS unit
  // t&3; global unit is XOR-swizzled by row bits 1-2.
  const int sr = t >> 2;                    // row within half (0..127)
  const int sc = (t & 3) ^ ((t >> 3) & 3);  // swizzled source 16B unit
  // pointers kept pointing at tile kt+2 inside the loop (init: tile 2)
  const unsigned char* srcA0 = A8 + (by * 256 + sr) * K_DIM + sc * 16 + 128;
  const unsigned char* srcA1 = A8 + (by * 256 + 128 + sr) * K_DIM + sc * 16 + 128;
  const unsigned char* srcB0 = B8 + (bx * 256 + sr) * K_DIM + sc * 16 + 128;
  const unsigned char* srcB1 = B8 + (bx * 256 + 128 + sr) * K_DIM + sc * 16 + 128;
  const int wofs = w * 1024;  // wave-uniform LDS dest base; HW adds lane*16

  // fragment geometry (mfma_scale 32x32x64): lane holds row lane&31,
  // K-units 2*(lane>>5), +1; swizzled positions p_lo, p_lo^1.
  const int r32 = lane & 31;
  const int key = (lane >> 1) & 3;
  const int p_lo = ((lane >> 5) << 1) ^ key;
  const int arow = wm * 128 + r32;  // + mi*32
  const int brow = wn * 64 + r32;   // + nj*32

  // ---- prologue: stage tile 0 -> buf0, tile 1 -> buf1 (order matters) ----
  gld_lds16(srcA0 - 128, sA + wofs);
  gld_lds16(srcA1 - 128, sA + 8192 + wofs);
  gld_lds16(srcB0 - 128, sB + wofs);
  gld_lds16(srcB1 - 128, sB + 8192 + wofs);
  gld_lds16(srcA0 - 64, sA + 16384 + wofs);
  gld_lds16(srcA1 - 64, sA + 16384 + 8192 + wofs);
  gld_lds16(srcB0 - 64, sB + 16384 + wofs);
  gld_lds16(srcB1 - 64, sB + 16384 + 8192 + wofs);
  asm volatile("s_waitcnt vmcnt(4)" ::: "memory");  // tile 0 landed
  BARRIER();                                        // publish

  int b = 0;  // buffer holding tile kt
  for (int kt = 0; kt < 64; ++kt) {
    int b2 = b + 2;
    if (b2 >= 3) b2 -= 3;
    const unsigned char* sAb = sA + b * 16384;
    const unsigned char* sBb = sB + b * 16384;
    unsigned char* dA = sA + b2 * 16384 + wofs;
    unsigned char* dB = sB + b2 * 16384 + wofs;
    const bool st = kt < 62;  // tile kt+2 exists

    // ---- phase A: B frags + A frags 0,1; stage A-halves of tile kt+2
    i32x8 bf0 = ldfrag(sBb + brow * 64, p_lo);
    i32x8 bf1 = ldfrag(sBb + (brow + 32) * 64, p_lo);
    i32x8 af0 = ldfrag(sAb + arow * 64, p_lo);
    i32x8 af1 = ldfrag(sAb + (arow + 32) * 64, p_lo);
    if (st) {
      gld_lds16(srcA0, dA);
      gld_lds16(srcA1, dA + 8192);
    }
    BARRIER();
    __builtin_amdgcn_s_setprio(1);
    acc[0][0] = MFMA_SC(af0, bf0, acc[0][0]);
    acc[0][1] = MFMA_SC(af0, bf1, acc[0][1]);
    acc[1][0] = MFMA_SC(af1, bf0, acc[1][0]);
    acc[1][1] = MFMA_SC(af1, bf1, acc[1][1]);
    __builtin_amdgcn_s_setprio(0);
    BARRIER();

    // ---- phase B: A frags 2,3; stage B-halves; counted vmcnt; publish
    af0 = ldfrag(sAb + (arow + 64) * 64, p_lo);
    af1 = ldfrag(sAb + (arow + 96) * 64, p_lo);
    if (st) {
      gld_lds16(srcB0, dB);
      gld_lds16(srcB1, dB + 8192);
    }
    BARRIER();
    __builtin_amdgcn_s_setprio(1);
    acc[2][0] = MFMA_SC(af0, bf0, acc[2][0]);
    acc[2][1] = MFMA_SC(af0, bf1, acc[2][1]);
    acc[3][0] = MFMA_SC(af1, bf0, acc[3][0]);
    acc[3][1] = MFMA_SC(af1, bf1, acc[3][1]);
    __builtin_amdgcn_s_setprio(0);
    if (st) {
      asm volatile("s_waitcnt vmcnt(4)" ::: "memory");  // tile kt+1 landed
    } else {
      asm volatile("s_waitcnt vmcnt(0)" ::: "memory");  // tail drain
    }
    BARRIER();  // publish tile kt+1

    srcA0 += 64; srcA1 += 64; srcB0 += 64; srcB1 += 64;
    if (++b == 3) b = 0;
  }

  // ---- epilogue: 32x32 C/D map: col = lane&31, row = (r&3)+8*(r>>2)+4*(lane>>5)
  const int mrow = 4 * (lane >> 5);
  const long gm_base = by * 256 + wm * 128;
  const long gn_base = bx * 256 + wn * 64 + r32;
#pragma unroll
  for (int nj = 0; nj < 2; ++nj) {
    const long gn = gn_base + nj * 32;
    const float bv = bias[gn];
#pragma unroll
    for (int mi = 0; mi < 4; ++mi) {
#pragma unroll
      for (int r = 0; r < 16; ++r) {
        const long gm = gm_base + mi * 32 + (r & 3) + 8 * (r >> 2) + mrow;
        C[gm * N_DIM + gn] = acc[mi][nj][r] * 4.0f + bv;
      }
    }
  }
}

// ---------------------------------------------------------------------------
// Fallback kernel (scratch-constrained paths): R2-verified 128x128 MX kernel
// with fused in-register quantization during staging.
// ---------------------------------------------------------------------------
template <bool FA, bool FB>
__global__ __launch_bounds__(256) void gemm_fp8_fb(const unsigned char* __restrict__ A8,
                                                   const float* __restrict__ Af,
                                                   const unsigned char* __restrict__ B8,
                                                   const float* __restrict__ Bf,
                                                   const float* __restrict__ bias,
                                                   float* __restrict__ C) {
  __shared__ unsigned char sA[128 * 64];
  __shared__ unsigned char sB[128 * 64];

  const int t = threadIdx.x;
  const int lane = t & 63;
  const int w = t >> 6;
  const int wm = w >> 1;
  const int wn = w & 1;
  const long bx = blockIdx.x;
  const long by = blockIdx.y;

  f32x16 acc[2][2] = {};

  const int l0 = w * 64 + lane;
  const int l1 = l0 + 256;
  const int r0 = l0 >> 2, c0 = (l0 & 3) ^ ((l0 >> 3) & 3);
  const int r1 = l1 >> 2, c1 = (l1 & 3) ^ ((l1 >> 3) & 3);

  const unsigned char* gA0 = nullptr; const unsigned char* gA1 = nullptr;
  const float* fA0 = nullptr;         const float* fA1 = nullptr;
  if constexpr (FA) {
    fA0 = Af + (by * 128 + r0) * K_DIM + c0 * 16;
    fA1 = Af + (by * 128 + r1) * K_DIM + c1 * 16;
  } else {
    gA0 = A8 + (by * 128 + r0) * K_DIM + c0 * 16;
    gA1 = A8 + (by * 128 + r1) * K_DIM + c1 * 16;
  }
  const unsigned char* gB0 = nullptr; const unsigned char* gB1 = nullptr;
  const float* fB0 = nullptr;         const float* fB1 = nullptr;
  if constexpr (FB) {
    fB0 = Bf + (bx * 128 + r0) * K_DIM + c0 * 16;
    fB1 = Bf + (bx * 128 + r1) * K_DIM + c1 * 16;
  } else {
    gB0 = B8 + (bx * 128 + r0) * K_DIM + c0 * 16;
    gB1 = B8 + (bx * 128 + r1) * K_DIM + c1 * 16;
  }

  unsigned char* lA0 = sA + w * 1024;
  unsigned char* lA1 = sA + 4096 + w * 1024;
  unsigned char* lB0 = sB + w * 1024;
  unsigned char* lB1 = sB + 4096 + w * 1024;

  const int r32 = lane & 31;
  const int key = (lane >> 1) & 3;
  const int p_lo = ((lane >> 5) << 1) ^ key;
  const unsigned char* sAw = sA + wm * 4096;
  const unsigned char* sBw = sB + wn * 4096;

  for (int kt = 0; kt < (int)(K_DIM / 64); ++kt) {
    if constexpr (FA) {
      *reinterpret_cast<uint4*>(sA + l0 * 16) = quant16(fA0, 0.5f);
      *reinterpret_cast<uint4*>(sA + l1 * 16) = quant16(fA1, 0.5f);
      fA0 += 64; fA1 += 64;
    } else {
      gld_lds16(gA0, lA0);
      gld_lds16(gA1, lA1);
      gA0 += 64; gA1 += 64;
    }
    if constexpr (FB) {
      *reinterpret_cast<uint4*>(sB + l0 * 16) = quant16(fB0, 1.0f);
      *reinterpret_cast<uint4*>(sB + l1 * 16) = quant16(fB1, 1.0f);
      fB0 += 64; fB1 += 64;
    } else {
      gld_lds16(gB0, lB0);
      gld_lds16(gB1, lB1);
      gB0 += 64; gB1 += 64;
    }
    __syncthreads();

    i32x8 af[2], bf[2];
#pragma unroll
    for (int i = 0; i < 2; ++i) {
      af[i] = ldfrag(sAw + (i * 32 + r32) * 64, p_lo);
      bf[i] = ldfrag(sBw + (i * 32 + r32) * 64, p_lo);
    }

#pragma unroll
    for (int i = 0; i < 2; ++i) {
#pragma unroll
      for (int j = 0; j < 2; ++j) {
        acc[i][j] = MFMA_SC(af[i], bf[j], acc[i][j]);
      }
    }
    __syncthreads();
  }

  const int mrow = 4 * (lane >> 5);
  const long gm_base = by * 128 + wm * 64;
  const long gn_base = bx * 128 + wn * 64 + r32;
#pragma unroll
  for (int nj = 0; nj < 2; ++nj) {
    const long gn = gn_base + nj * 32;
    const float bv = bias[gn];
#pragma unroll
    for (int mi = 0; mi < 2; ++mi) {
#pragma unroll
      for (int r = 0; r < 16; ++r) {
        const long gm = gm_base + mi * 32 + (r & 3) + 8 * (r >> 2) + mrow;
        C[gm * N_DIM + gn] = acc[mi][nj][r] * 4.0f + bv;
      }
    }
  }
}

// ---------------------------------------------------------------------------
extern "C" void kernel_launch(void* const* d_in, const int* in_sizes, int n_in,
                              void* d_out, int out_size, void* d_ws, size_t ws_size,
                              hipStream_t stream) {
  const float* inp = (const float*)d_in[0];   // [4,4096,4096] f32
  const float* wgt = (const float*)d_in[1];   // [4096,4096] f32 (fp8 values upcast by harness)
  const float* bias = (const float*)d_in[2];  // [4096] f32
  float* out = (float*)d_out;

  const size_t A_BYTES = (size_t)(M_DIM * K_DIM);  // 64 MB
  const size_t B_BYTES = (size_t)(N_DIM * K_DIM);  // 16 MB

  if (ws_size >= A_BYTES + B_BYTES) {
    // main path: pre-quantize both operands into d_ws, 256^2 pipelined GEMM
    unsigned char* aq = (unsigned char*)d_ws;
    unsigned char* wq = (unsigned char*)d_ws + A_BYTES;
    quant_fp8<<<dim3((unsigned)(M_DIM * K_DIM / 1024)), dim3(256), 0, stream>>>(
        inp, (unsigned int*)aq, 0.5f);
    quant_fp8<<<dim3((unsigned)(N_DIM * K_DIM / 1024)), dim3(256), 0, stream>>>(
        wgt, (unsigned int*)wq, 1.0f);
    gemm_fp8_256<<<dim3(16, 64), dim3(512), 0, stream>>>(aq, wq, bias, out);
  } else if (ws_size >= B_BYTES) {
    unsigned char* wq = (unsigned char*)d_ws;
    quant_fp8<<<dim3((unsigned)(N_DIM * K_DIM / 1024)), dim3(256), 0, stream>>>(
        wgt, (unsigned int*)wq, 1.0f);
    gemm_fp8_fb<true, false><<<dim3((unsigned)(N_DIM / 128), (unsigned)(M_DIM / 128)),
                               dim3(256), 0, stream>>>(nullptr, inp, wq, nullptr, bias, out);
  } else {
    gemm_fp8_fb<true, true><<<dim3((unsigned)(N_DIM / 128), (unsigned)(M_DIM / 128)),
                              dim3(256), 0, stream>>>(nullptr, inp, nullptr, wgt, bias, out);
  }
}

// Round 5
// 785.172 us; speedup vs baseline: 1.0450x; 1.0070x over previous
//
#include <hip/hip_runtime.h>

typedef float f32x4 __attribute__((ext_vector_type(4)));
typedef float f32x16 __attribute__((ext_vector_type(16)));
typedef int i32x4 __attribute__((ext_vector_type(4)));
typedef int i32x8 __attribute__((ext_vector_type(8)));

#define M_DIM 16384L
#define N_DIM 4096L
#define K_DIM 4096L

// ---------------------------------------------------------------------------
// f32 -> OCP e4m3fn, RNE + saturation, bit-exact software version.
// ---------------------------------------------------------------------------
__device__ __forceinline__ unsigned int f32_to_e4m3(float x, float scale) {
  float v = fminf(fmaxf(x * scale, -448.f), 448.f);
  unsigned int u = __float_as_uint(v);
  unsigned int s = (u >> 24) & 0x80u;
  float ax = fabsf(v);
  unsigned int ua = __float_as_uint(ax);
  unsigned int subn = (unsigned int)rintf(ax * 512.0f);   // 0..8, RNE (subnormals)
  unsigned int r = ua + 0x7FFFFu + ((ua >> 20) & 1u);     // RNE to 3 mantissa bits
  unsigned int nrm = ((r >> 20) & 0x7FFu) - 960u;         // rebias 127 -> 7
  unsigned int mag = (ax < 0.015625f) ? subn : nrm;
  return mag | s;
}

__device__ __forceinline__ unsigned int pack4_e4m3(float4 v, float scale) {
  return f32_to_e4m3(v.x, scale) | (f32_to_e4m3(v.y, scale) << 8) |
         (f32_to_e4m3(v.z, scale) << 16) | (f32_to_e4m3(v.w, scale) << 24);
}

// ---------------------------------------------------------------------------
// Kernel 1: f32 -> packed e4m3 quantize (memory-bound).
// ---------------------------------------------------------------------------
__global__ __launch_bounds__(256) void quant_fp8(const float* __restrict__ in,
                                                 unsigned int* __restrict__ out,
                                                 float scale) {
  const long i = (long)blockIdx.x * 256 + threadIdx.x;
  out[i] = pack4_e4m3(reinterpret_cast<const float4*>(in)[i], scale);
}

// ---------------------------------------------------------------------------
// Shared helpers
// ---------------------------------------------------------------------------
__device__ __forceinline__ void gld_lds16(const unsigned char* g, unsigned char* l) {
  __builtin_amdgcn_global_load_lds(
      (const __attribute__((address_space(1))) unsigned int*)g,
      (__attribute__((address_space(3))) unsigned int*)l,
      16, 0, 0);
}

__device__ __forceinline__ uint4 quant16(const float* p, float scale) {
  const float4* q = reinterpret_cast<const float4*>(p);
  uint4 r;
  r.x = pack4_e4m3(q[0], scale);
  r.y = pack4_e4m3(q[1], scale);
  r.z = pack4_e4m3(q[2], scale);
  r.w = pack4_e4m3(q[3], scale);
  return r;
}

// two ds_read_b128 at swizzled 16B units p_lo, p_lo^1 -> 32B K-fragment
__device__ __forceinline__ i32x8 ldfrag(const unsigned char* p, int p_lo) {
  i32x4 lo = *reinterpret_cast<const i32x4*>(p + p_lo * 16);
  i32x4 hi = *reinterpret_cast<const i32x4*>(p + (p_lo ^ 1) * 16);
  return i32x8{lo[0], lo[1], lo[2], lo[3], hi[0], hi[1], hi[2], hi[3]};
}

// fmtA=fmtB=0 (e4m3), scales = e8m0 127 = 1.0 -> bit-exact plain fp8 matmul
#define MFMA_SC(a, b, c) \
  __builtin_amdgcn_mfma_scale_f32_32x32x64_f8f6f4((a), (b), (c), 0, 0, 0, 0x7F7F7F7F, 0, 0x7F7F7F7F)

#define BARRIER() asm volatile("s_barrier" ::: "memory")

// ---------------------------------------------------------------------------
// Kernel 2 (main path): 128x128 tile, BK=64, 4 waves — R2's verified geometry
// (fragments, swizzle, epilogue byte-identical) with the counted-vmcnt
// pipeline from R3/R4:
//   * triple-buffered LDS (3 x 16 KB = 48 KB -> 3 blocks/CU, TLP does the
//     LDS<->MFMA overlap that R3/R4's 1-block lockstep could not)
//   * ONE s_barrier per K-tile: publishes tile kt+1 (after vmcnt(4), which
//     retires exactly its 4 loads — never drains to 0 in steady state) AND
//     protects buffer kt-1 from next iter's staging.
//
// Ledger (per thread, 4 loads/K-tile, in-order retirement):
//   prologue: stage tile0 -> buf0 (4 loads), tile1 -> buf1 (4); vmcnt(4)
//   retires tile0's; barrier publishes.  Enter iter 0 with 4 outstanding.
//   iter kt: issue tile kt+2's 4 loads into buf[(kt+2)%3] (safe: its last
//   reader finished at end-of-iter kt-1 barrier); ds_read frags of tile kt
//   from buf[kt%3]; 4 MFMA; vmcnt(4) retires tile kt+1's 4 (oldest of 8);
//   barrier publishes tile kt+1.  Tail: kt>=62 stages nothing, vmcnt(0).
// ---------------------------------------------------------------------------
__global__ __launch_bounds__(256, 3) void gemm_fp8_128(
    const unsigned char* __restrict__ A8, const unsigned char* __restrict__ B8,
    const float* __restrict__ bias, float* __restrict__ C) {
  __shared__ unsigned char sA[3 * 8192];
  __shared__ unsigned char sB[3 * 8192];

  const int t = threadIdx.x;
  const int lane = t & 63;
  const int w = t >> 6;   // wave 0..3
  const int wm = w >> 1;  // 2x2 wave grid, each wave owns 64x64 of C
  const int wn = w & 1;
  const long bx = blockIdx.x;  // N tile (32)
  const long by = blockIdx.y;  // M tile (128)

  f32x16 acc[2][2] = {};

  // staging: per K-tile 512 chunks of 16 B per operand; thread stages chunks
  // l0 = t and l1 = t+256 of each. chunk l -> row l>>2, LDS unit l&3; the
  // global source unit is XOR-swizzled by row bits 1-2 (involution):
  //   LDS (row, unit p) holds global unit p ^ ((row>>1)&3).
  const int l0 = t;
  const int l1 = t + 256;
  const int r0 = l0 >> 2, c0 = (l0 & 3) ^ ((l0 >> 3) & 3);
  const int r1 = l1 >> 2, c1 = (l1 & 3) ^ ((l1 >> 3) & 3);

  // pointers kept pointing at tile kt+2 inside the loop (init: tile 2)
  const unsigned char* gA0 = A8 + (by * 128 + r0) * K_DIM + c0 * 16 + 128;
  const unsigned char* gA1 = A8 + (by * 128 + r1) * K_DIM + c1 * 16 + 128;
  const unsigned char* gB0 = B8 + (bx * 128 + r0) * K_DIM + c0 * 16 + 128;
  const unsigned char* gB1 = B8 + (bx * 128 + r1) * K_DIM + c1 * 16 + 128;
  const int wofs = w * 1024;  // wave-uniform LDS dest base; HW adds lane*16

  // fragment geometry (mfma_scale 32x32x64): lane holds row lane&31,
  // K-units 2*(lane>>5), +1; swizzled positions p_lo, p_lo^1.
  const int r32 = lane & 31;
  const int key = (lane >> 1) & 3;
  const int p_lo = ((lane >> 5) << 1) ^ key;

  // ---- prologue: stage tile 0 -> buf0, tile 1 -> buf1 (tile order matters)
  gld_lds16(gA0 - 128, sA + wofs);
  gld_lds16(gA1 - 128, sA + 4096 + wofs);
  gld_lds16(gB0 - 128, sB + wofs);
  gld_lds16(gB1 - 128, sB + 4096 + wofs);
  gld_lds16(gA0 - 64, sA + 8192 + wofs);
  gld_lds16(gA1 - 64, sA + 8192 + 4096 + wofs);
  gld_lds16(gB0 - 64, sB + 8192 + wofs);
  gld_lds16(gB1 - 64, sB + 8192 + 4096 + wofs);
  asm volatile("s_waitcnt vmcnt(4)" ::: "memory");  // tile 0 landed
  BARRIER();                                        // publish

  int b = 0;  // buffer holding tile kt
  for (int kt = 0; kt < 64; ++kt) {
    int b2 = b + 2;
    if (b2 >= 3) b2 -= 3;
    const bool st = kt < 62;  // tile kt+2 exists

    if (st) {  // issue next-next tile's loads first: max in-flight time
      unsigned char* dA = sA + b2 * 8192 + wofs;
      unsigned char* dB = sB + b2 * 8192 + wofs;
      gld_lds16(gA0, dA);
      gld_lds16(gA1, dA + 4096);
      gld_lds16(gB0, dB);
      gld_lds16(gB1, dB + 4096);
      gA0 += 64; gA1 += 64; gB0 += 64; gB1 += 64;
    }

    const unsigned char* sAw = sA + b * 8192 + wm * 4096;
    const unsigned char* sBw = sB + b * 8192 + wn * 4096;
    i32x8 af0 = ldfrag(sAw + r32 * 64, p_lo);
    i32x8 bf0 = ldfrag(sBw + r32 * 64, p_lo);
    i32x8 af1 = ldfrag(sAw + (32 + r32) * 64, p_lo);
    i32x8 bf1 = ldfrag(sBw + (32 + r32) * 64, p_lo);

    __builtin_amdgcn_s_setprio(1);
    acc[0][0] = MFMA_SC(af0, bf0, acc[0][0]);
    acc[0][1] = MFMA_SC(af0, bf1, acc[0][1]);
    acc[1][0] = MFMA_SC(af1, bf0, acc[1][0]);
    acc[1][1] = MFMA_SC(af1, bf1, acc[1][1]);
    __builtin_amdgcn_s_setprio(0);

    if (st) {
      asm volatile("s_waitcnt vmcnt(4)" ::: "memory");  // tile kt+1 landed
    } else {
      asm volatile("s_waitcnt vmcnt(0)" ::: "memory");  // tail drain
    }
    BARRIER();  // publish tile kt+1 + release buf kt-1 for staging

    if (++b == 3) b = 0;
  }

  // ---- epilogue: 32x32 C/D map: col = lane&31, row = (r&3)+8*(r>>2)+4*(lane>>5)
  const int mrow = 4 * (lane >> 5);
  const long gm_base = by * 128 + wm * 64;
  const long gn_base = bx * 128 + wn * 64 + r32;
#pragma unroll
  for (int nj = 0; nj < 2; ++nj) {
    const long gn = gn_base + nj * 32;
    const float bv = bias[gn];
#pragma unroll
    for (int mi = 0; mi < 2; ++mi) {
#pragma unroll
      for (int r = 0; r < 16; ++r) {
        const long gm = gm_base + mi * 32 + (r & 3) + 8 * (r >> 2) + mrow;
        C[gm * N_DIM + gn] = acc[mi][nj][r] * 4.0f + bv;
      }
    }
  }
}

// ---------------------------------------------------------------------------
// Fallback kernel (scratch-constrained paths): R2-verified 128x128 MX kernel
// with fused in-register quantization during staging.
// ---------------------------------------------------------------------------
template <bool FA, bool FB>
__global__ __launch_bounds__(256) void gemm_fp8_fb(const unsigned char* __restrict__ A8,
                                                   const float* __restrict__ Af,
                                                   const unsigned char* __restrict__ B8,
                                                   const float* __restrict__ Bf,
                                                   const float* __restrict__ bias,
                                                   float* __restrict__ C) {
  __shared__ unsigned char sA[128 * 64];
  __shared__ unsigned char sB[128 * 64];

  const int t = threadIdx.x;
  const int lane = t & 63;
  const int w = t >> 6;
  const int wm = w >> 1;
  const int wn = w & 1;
  const long bx = blockIdx.x;
  const long by = blockIdx.y;

  f32x16 acc[2][2] = {};

  const int l0 = w * 64 + lane;
  const int l1 = l0 + 256;
  const int r0 = l0 >> 2, c0 = (l0 & 3) ^ ((l0 >> 3) & 3);
  const int r1 = l1 >> 2, c1 = (l1 & 3) ^ ((l1 >> 3) & 3);

  const unsigned char* gA0 = nullptr; const unsigned char* gA1 = nullptr;
  const float* fA0 = nullptr;         const float* fA1 = nullptr;
  if constexpr (FA) {
    fA0 = Af + (by * 128 + r0) * K_DIM + c0 * 16;
    fA1 = Af + (by * 128 + r1) * K_DIM + c1 * 16;
  } else {
    gA0 = A8 + (by * 128 + r0) * K_DIM + c0 * 16;
    gA1 = A8 + (by * 128 + r1) * K_DIM + c1 * 16;
  }
  const unsigned char* gB0 = nullptr; const unsigned char* gB1 = nullptr;
  const float* fB0 = nullptr;         const float* fB1 = nullptr;
  if constexpr (FB) {
    fB0 = Bf + (bx * 128 + r0) * K_DIM + c0 * 16;
    fB1 = Bf + (bx * 128 + r1) * K_DIM + c1 * 16;
  } else {
    gB0 = B8 + (bx * 128 + r0) * K_DIM + c0 * 16;
    gB1 = B8 + (bx * 128 + r1) * K_DIM + c1 * 16;
  }

  unsigned char* lA0 = sA + w * 1024;
  unsigned char* lA1 = sA + 4096 + w * 1024;
  unsigned char* lB0 = sB + w * 1024;
  unsigned char* lB1 = sB + 4096 + w * 1024;

  const int r32 = lane & 31;
  const int key = (lane >> 1) & 3;
  const int p_lo = ((lane >> 5) << 1) ^ key;
  const unsigned char* sAw = sA + wm * 4096;
  const unsigned char* sBw = sB + wn * 4096;

  for (int kt = 0; kt < (int)(K_DIM / 64); ++kt) {
    if constexpr (FA) {
      *reinterpret_cast<uint4*>(sA + l0 * 16) = quant16(fA0, 0.5f);
      *reinterpret_cast<uint4*>(sA + l1 * 16) = quant16(fA1, 0.5f);
      fA0 += 64; fA1 += 64;
    } else {
      gld_lds16(gA0, lA0);
      gld_lds16(gA1, lA1);
      gA0 += 64; gA1 += 64;
    }
    if constexpr (FB) {
      *reinterpret_cast<uint4*>(sB + l0 * 16) = quant16(fB0, 1.0f);
      *reinterpret_cast<uint4*>(sB + l1 * 16) = quant16(fB1, 1.0f);
      fB0 += 64; fB1 += 64;
    } else {
      gld_lds16(gB0, lB0);
      gld_lds16(gB1, lB1);
      gB0 += 64; gB1 += 64;
    }
    __syncthreads();

    i32x8 af[2], bf[2];
#pragma unroll
    for (int i = 0; i < 2; ++i) {
      af[i] = ldfrag(sAw + (i * 32 + r32) * 64, p_lo);
      bf[i] = ldfrag(sBw + (i * 32 + r32) * 64, p_lo);
    }

#pragma unroll
    for (int i = 0; i < 2; ++i) {
#pragma unroll
      for (int j = 0; j < 2; ++j) {
        acc[i][j] = MFMA_SC(af[i], bf[j], acc[i][j]);
      }
    }
    __syncthreads();
  }

  const int mrow = 4 * (lane >> 5);
  const long gm_base = by * 128 + wm * 64;
  const long gn_base = bx * 128 + wn * 64 + r32;
#pragma unroll
  for (int nj = 0; nj < 2; ++nj) {
    const long gn = gn_base + nj * 32;
    const float bv = bias[gn];
#pragma unroll
    for (int mi = 0; mi < 2; ++mi) {
#pragma unroll
      for (int r = 0; r < 16; ++r) {
        const long gm = gm_base + mi * 32 + (r & 3) + 8 * (r >> 2) + mrow;
        C[gm * N_DIM + gn] = acc[mi][nj][r] * 4.0f + bv;
      }
    }
  }
}

// ---------------------------------------------------------------------------
extern "C" void kernel_launch(void* const* d_in, const int* in_sizes, int n_in,
                              void* d_out, int out_size, void* d_ws, size_t ws_size,
                              hipStream_t stream) {
  const float* inp = (const float*)d_in[0];   // [4,4096,4096] f32
  const float* wgt = (const float*)d_in[1];   // [4096,4096] f32 (fp8 values upcast by harness)
  const float* bias = (const float*)d_in[2];  // [4096] f32
  float* out = (float*)d_out;

  const size_t A_BYTES = (size_t)(M_DIM * K_DIM);  // 64 MB
  const size_t B_BYTES = (size_t)(N_DIM * K_DIM);  // 16 MB

  if (ws_size >= A_BYTES + B_BYTES) {
    // main path: pre-quantize both operands into d_ws, pipelined 128^2 GEMM
    unsigned char* aq = (unsigned char*)d_ws;
    unsigned char* wq = (unsigned char*)d_ws + A_BYTES;
    quant_fp8<<<dim3((unsigned)(M_DIM * K_DIM / 1024)), dim3(256), 0, stream>>>(
        inp, (unsigned int*)aq, 0.5f);
    quant_fp8<<<dim3((unsigned)(N_DIM * K_DIM / 1024)), dim3(256), 0, stream>>>(
        wgt, (unsigned int*)wq, 1.0f);
    gemm_fp8_128<<<dim3((unsigned)(N_DIM / 128), (unsigned)(M_DIM / 128)),
                   dim3(256), 0, stream>>>(aq, wq, bias, out);
  } else if (ws_size >= B_BYTES) {
    unsigned char* wq = (unsigned char*)d_ws;
    quant_fp8<<<dim3((unsigned)(N_DIM * K_DIM / 1024)), dim3(256), 0, stream>>>(
        wgt, (unsigned int*)wq, 1.0f);
    gemm_fp8_fb<true, false><<<dim3((unsigned)(N_DIM / 128), (unsigned)(M_DIM / 128)),
                               dim3(256), 0, stream>>>(nullptr, inp, wq, nullptr, bias, out);
  } else {
    gemm_fp8_fb<true, true><<<dim3((unsigned)(N_DIM / 128), (unsigned)(M_DIM / 128)),
                              dim3(256), 0, stream>>>(nullptr, inp, nullptr, wgt, bias, out);
  }
}